// Round 6
// baseline (298.682 us; speedup 1.0000x reference)
//
#include <hip/hip_runtime.h>
#include <hip/hip_bf16.h>

// FixedPointLayer: x_{k+1} = tanh(GAMMA * A_h @ x_k + b_h). fp32 in/out.
// Round-15: tagged-data exchange -- ONE contended access per step.
// R10/R11/R14 all measured ~7.5us/step across three different sync
// protocols => the cost is the COUNT of serialized grid-contended
// uncached accesses (reload, flag-check, poll, re-read; each ~1-1.5us
// under 4096-wave contention), not the waiting itself. Fix: publish each
// row as an 8-B {bits(x), level_tag} pair with one dwordx2 sc0sc1 store
// (value+tag commit atomically: one instruction, one line, one coherence
// transaction). Readers accept iff all 4 tags in their 2xdwordx4 reload
// are >= level i-1 -- the acceptance check rides in the data they load
// anyway. Staleness<=1 async Jacobi proven on-HW in R14 (rate <=0.6
// worst/~0.4 typ; 13 steps => residual << 2e-3 int8 quant floor; absmax
// was bit-identical). Deleted from the critical path: flag store, store
// drain, flag-check RTT, poll RTT, re-read RTT, one __syncthreads.
// Tags are epoch-namespaced (g_epoch bumped per launch; no reset pass,
// replay-safe). Every poll POLL_CAP-bounded: fail visibly, never hang.

#define FPL_GAMMA 0.9f
#define INT8_STEPS 13           // async steps (staleness-1 insurance margin)
#define FB_STEPS 15             // fallback keeps original count
#define COOP_H 8
#define COOP_N 2048
#define COOP_HN (COOP_H * COOP_N)
#define MAX_HN 65536
#define SWZ4(i) ((i) ^ (((i) >> 3) & 7))   // float4-index LDS swizzle for xs
#define POLL_CAP (1u << 22)                // safety valve: fail, don't hang

__device__ float g_x[2][MAX_HN];                 // fallback ping-pong iterate
__device__ __align__(16) uint2 g_xt[MAX_HN];     // coop: {bits(x), tag} per row
__device__ int   g_is_f32;                       // 1 if fp32 inputs, 0 if bf16
__device__ unsigned int g_epoch;                 // bumped by probe each launch

__device__ __forceinline__ float bf2f(unsigned short u) {
    union { unsigned int i; float f; } v; v.i = ((unsigned int)u) << 16; return v.f;
}

// ---- proven system-scope transport (R11/R14: correct 3x on HW) ----
// sc0 sc1: bypass L0 + XCD-L2 both ways; stores commit at the coherence
// point; loads read the coherence point (vmcnt ack = commit).
__device__ __forceinline__ unsigned int ld_cp32(const void* p) {
    unsigned int r;
    asm volatile("global_load_dword %0, %1, off sc0 sc1\n\ts_waitcnt vmcnt(0)"
                 : "=v"(r) : "v"(p) : "memory");
    return r;
}
__device__ __forceinline__ void st_cp64(void* p, uint2 v) {
    asm volatile("global_store_dwordx2 %0, %1, off sc0 sc1"
                 :: "v"(p), "v"(v) : "memory");
}
// two dwordx4 issued back-to-back, single wait: rows 4t..4t+3 + tags
__device__ __forceinline__ void ld2_cp128(const void* p, uint4& a, uint4& b) {
    asm volatile("global_load_dwordx4 %0, %2, off sc0 sc1\n\t"
                 "global_load_dwordx4 %1, %3, off sc0 sc1\n\t"
                 "s_waitcnt vmcnt(0)"
                 : "=&v"(a), "=&v"(b)
                 : "v"(p), "v"((const void*)((const char*)p + 16))
                 : "memory");
}

// Input dtype probe (parallelized) + epoch bump (tag namespace: no reset
// pass needed, graph-replay safe -- stale tags are < this launch's base).
__global__ __launch_bounds__(256) void fpl_probe(const unsigned short* __restrict__ A) {
    const int t = threadIdx.x;
    if (t == 0) g_epoch = g_epoch + 1u;
    if (t < 64) {
        int bad = 0;
#pragma unroll
        for (int k = 0; k < 4; ++k) {
            const float av = fabsf(bf2f(A[(t << 2) + k]));
            if (!(av <= 1e3f)) bad = 1;
        }
        const unsigned long long any = __ballot(bad);
        if (t == 0) g_is_f32 = (any != 0ull) ? 1 : 0;
    }
}

// x1 = tanh(b) into g_x[0] -- FALLBACK path only (coop computes x1 locally).
__global__ __launch_bounds__(256) void fpl_init(const void* __restrict__ bv, int hn) {
    int i = blockIdx.x * 256 + threadIdx.x;
    if (i < hn) {
        float bval = g_is_f32 ? ((const float*)bv)[i]
                              : bf2f(((const unsigned short*)bv)[i]);
        g_x[0][i] = tanhf(bval);
    }
}

// Decode 4 int8 lanes of w against float4 x into acc.
__device__ __forceinline__ float dec4(unsigned int w, const float4 x, float acc) {
    acc = fmaf((float)((int)(w << 24) >> 24), x.x, acc);
    acc = fmaf((float)((int)(w << 16) >> 24), x.y, acc);
    acc = fmaf((float)((int)(w <<  8) >> 24), x.z, acc);
    acc = fmaf((float)((int)w >> 24),         x.w, acc);
    return acc;
}

// Quantize one row (held in v4[8], this wave's 2048 cols) into LDS int8.
__device__ __forceinline__ void quant_row(const float4* v4, int lrow, int lane,
                                          unsigned int* aq, float* rowscale) {
    float m = 0.f;
#pragma unroll
    for (int k = 0; k < 8; ++k)
        m = fmaxf(m, fmaxf(fmaxf(fabsf(v4[k].x), fabsf(v4[k].y)),
                           fmaxf(fabsf(v4[k].z), fabsf(v4[k].w))));
#pragma unroll
    for (int off = 32; off > 0; off >>= 1)
        m = fmaxf(m, __shfl_xor(m, off, 64));
    m = fmaxf(m, 1e-30f);
    const float inv = 127.0f / m;
    if (lane == 0) rowscale[lrow] = m * (1.0f / 127.0f);
    unsigned int* aqr = aq + lrow * 512;
#pragma unroll
    for (int k = 0; k < 8; ++k) {
        const int q0 = (int)rintf(v4[k].x * inv);
        const int q1 = (int)rintf(v4[k].y * inv);
        const int q2 = (int)rintf(v4[k].z * inv);
        const int q3 = (int)rintf(v4[k].w * inv);
        aqr[(k << 6) + lane] = (unsigned int)(q0 & 255)
                             | ((unsigned int)(q1 & 255) << 8)
                             | ((unsigned int)(q2 & 255) << 16)
                             | ((unsigned int)(q3 & 255) << 24);
    }
}

// ---------------- persistent cooperative solver ----------------
// Grid 256 x 512 (1 block/CU by LDS). 32 blocks/head, 64 rows/block.
__global__ __launch_bounds__(512)
void fpl_coop(const void* __restrict__ Av,
              const void* __restrict__ bv,
              float* __restrict__ out) {
    __shared__ unsigned int aq[64 * 512];   // 64 rows x 2048 int8 = 128 KiB
    __shared__ float xs[COOP_N];            // 8 KiB: head's x (SWZ4 layout)
    __shared__ float red[64 * 65];          // 16.6 KiB: partials, padded
    __shared__ float rowscale[64];          // 256 B
    __shared__ unsigned int sh_base;        // epoch<<6 (tag namespace)

    const int tid  = threadIdx.x;
    const int wave = tid >> 6;
    const int lane = tid & 63;
    const int bid  = blockIdx.x;             // 0..255
    const int head = bid & 7;
    const int jblk = bid >> 3;               // block index within head, 0..31
    const int rowBase = jblk << 6;           // 64 rows/block
    const bool isf32 = (g_is_f32 != 0);      // wave-uniform
    const int lrow0 = wave << 3;             // wave's first local row

    if (tid == 0) sh_base = ld_cp32(&g_epoch) << 6;

    // ---- prologue: quantize my wave's 8 rows into LDS int8 ----
    if (isf32) {
        // 2-deep pipelined: issue row r+1 loads before quantizing row r.
        const float* Ab = (const float*)Av;
        const size_t grow0 = (size_t)(head * COOP_N + rowBase + lrow0);
        float4 cur[8], nxt[8];
        {
            const float* Ar = Ab + (grow0 << 11);
#pragma unroll
            for (int k = 0; k < 8; ++k)
                cur[k] = *(const float4*)(Ar + ((k << 8) + (lane << 2)));
        }
#pragma unroll 1
        for (int r = 0; r < 8; ++r) {
            if (r < 7) {
                const float* Ar = Ab + ((grow0 + r + 1) << 11);
#pragma unroll
                for (int k = 0; k < 8; ++k)
                    nxt[k] = *(const float4*)(Ar + ((k << 8) + (lane << 2)));
            }
            quant_row(cur, lrow0 + r, lane, aq, rowscale);
#pragma unroll
            for (int k = 0; k < 8; ++k) cur[k] = nxt[k];
        }
    } else {
#pragma unroll 1
        for (int r = 0; r < 8; ++r) {
            const int lrow = lrow0 + r;
            const size_t grow = (size_t)(head * COOP_N + rowBase + lrow);
            const unsigned short* Ar = (const unsigned short*)Av + (grow << 11);
            float4 v4[8];
#pragma unroll
            for (int k = 0; k < 8; ++k) {
                const ushort4 t = *(const ushort4*)(Ar + ((k << 8) + (lane << 2)));
                v4[k] = make_float4(bf2f(t.x), bf2f(t.y), bf2f(t.z), bf2f(t.w));
            }
            quant_row(v4, lrow, lane, aq, rowscale);
        }
    }

    // ---- local x1 = tanh(b): every block fills the head's FULL x1 in LDS ----
    {
        float4 bb;
        if (isf32) bb = ((const float4*)bv)[(head << 9) + tid];
        else {
            const ushort4 t = ((const ushort4*)bv)[(head << 9) + tid];
            bb = make_float4(bf2f(t.x), bf2f(t.y), bf2f(t.z), bf2f(t.w));
        }
        ((float4*)xs)[SWZ4(tid)] =
            make_float4(tanhf(bb.x), tanhf(bb.y), tanhf(bb.z), tanhf(bb.w));
    }

    // Writer threads (tid%8==0) own local row rl=tid>>3; preload b.
    const int rl   = tid >> 3;               // 0..63
    const int gRow = head * COOP_N + rowBase + rl;
    float breg = 0.f;
    if ((tid & 7) == 0)
        breg = isf32 ? ((const float*)bv)[gRow]
                     : bf2f(((const unsigned short*)bv)[gRow]);

    __syncthreads();                          // aq + rowscale + xs + sh_base
    const unsigned int base = sh_base;        // tag namespace for this launch
    const float sreg = rowscale[rl];          // writer's row scale
    const float4* xsf4 = (const float4*)xs;
    const int c = tid & 7;                    // writer iff c==0

    // publish my level-1 chunk {tanh(b), base+1} (same bits as LDS x1)
    if (c == 0)
        st_cp64(&g_xt[gRow], make_uint2(__float_as_uint(tanhf(breg)), base + 1u));

    const uint4* const gx4 = (const uint4*)&g_xt[head << 11]; // 1024 uint4/head

    // ---- async int8 iterations; input level i in xs, output level i+1 ----
    for (int i = 1; i <= INT8_STEPS; ++i) {
        float acc[8];
#pragma unroll
        for (int r = 0; r < 8; ++r) acc[r] = 0.f;
#pragma unroll
        for (int j = 0; j < 2; ++j) {
            const int bb = (j << 8) + (lane << 2);       // f4 idx == u32 idx
            const float4 x0 = xsf4[SWZ4(bb + 0)];
            const float4 x1 = xsf4[SWZ4(bb + 1)];
            const float4 x2 = xsf4[SWZ4(bb + 2)];
            const float4 x3 = xsf4[SWZ4(bb + 3)];
#pragma unroll
            for (int r = 0; r < 8; ++r) {
                const uint4 w = *(const uint4*)(aq + (lrow0 + r) * 512 + bb);
                float a = acc[r];
                a = dec4(w.x, x0, a);
                a = dec4(w.y, x1, a);
                a = dec4(w.z, x2, a);
                a = dec4(w.w, x3, a);
                acc[r] = a;
            }
        }

        // transpose partials via LDS (stride 65 -> conflict-free)
#pragma unroll
        for (int r = 0; r < 8; ++r)
            red[(lrow0 + r) * 65 + lane] = acc[r];
        __syncthreads();                                  // (sync2)

        // thread t: row rl=t>>3, chunk c=t&7: serial-8 + 3-level butterfly
        const float* rr = &red[rl * 65 + (c << 3)];
        float v = ((rr[0] + rr[1]) + (rr[2] + rr[3]))
                + ((rr[4] + rr[5]) + (rr[6] + rr[7]));
        v += __shfl_xor(v, 1, 64);
        v += __shfl_xor(v, 2, 64);
        v += __shfl_xor(v, 4, 64);

        // publish level i+1 chunk: ONE atomic 8-B {value, tag} store.
        // No drain, no flag: the tag IS the ordering.
        if (c == 0)
            st_cp64(&g_xt[gRow],
                    make_uint2(__float_as_uint(tanhf(FPL_GAMMA * sreg * v + breg)),
                               base + (unsigned int)(i + 1)));

        if (i < INT8_STEPS) {
            // consume input for iter i+1: accept level >= i (staleness<=1).
            // My own rows' previous tag (base+i) already passes -> no
            // self-wait on the store just issued. Peers' level-i stores
            // landed a full step ago; level-(i+1) typically visible too.
            const unsigned int need = base + (unsigned int)i;
            uint4 a, b;
            for (unsigned int it = 0; it < POLL_CAP; ++it) {
                ld2_cp128(gx4 + (tid << 1), a, b);
                const int ok = (a.y >= need) & (a.w >= need)
                             & (b.y >= need) & (b.w >= need);
                if (__all(ok)) break;
                __builtin_amdgcn_s_sleep(1);
            }
            ((float4*)xs)[SWZ4(tid)] =
                make_float4(__uint_as_float(a.x), __uint_as_float(a.z),
                            __uint_as_float(b.x), __uint_as_float(b.z));
            __syncthreads();                              // (sync1, next iter)
        }
    }

    // ---- one true barrier: all rows at final level S+1, then exact step ----
    {
        const unsigned int need = base + (unsigned int)(INT8_STEPS + 1);
        uint4 a, b;
        for (unsigned int it = 0; it < POLL_CAP; ++it) {
            ld2_cp128(gx4 + (tid << 1), a, b);
            const int ok = (a.y >= need) & (a.w >= need)
                         & (b.y >= need) & (b.w >= need);
            if (__all(ok)) break;
            __builtin_amdgcn_s_sleep(1);
        }
        ((float4*)xs)[SWZ4(tid)] =
            make_float4(__uint_as_float(a.x), __uint_as_float(a.z),
                        __uint_as_float(b.x), __uint_as_float(b.z));
        __syncthreads();
    }

    // ---- final differentiable step with EXACT A (streamed, L3-resident) ----
#pragma unroll 1
    for (int r = 0; r < 8; ++r) {
        const int lrow = lrow0 + r;
        const size_t grow = (size_t)(head * COOP_N + rowBase + lrow);
        float acc = 0.f;
        if (isf32) {
            const float* Ar = (const float*)Av + (grow << 11);
#pragma unroll
            for (int k = 0; k < 8; ++k) {
                const float4 a = *(const float4*)(Ar + ((k << 8) + (lane << 2)));
                const float4 x = xsf4[SWZ4((k << 6) + lane)];
                acc += a.x * x.x + a.y * x.y + a.z * x.z + a.w * x.w;
            }
        } else {
            const unsigned short* Ar = (const unsigned short*)Av + (grow << 11);
#pragma unroll
            for (int k = 0; k < 8; ++k) {
                const ushort4 t = *(const ushort4*)(Ar + ((k << 8) + (lane << 2)));
                const float4 x = xsf4[SWZ4((k << 6) + lane)];
                acc += bf2f(t.x) * x.x + bf2f(t.y) * x.y
                     + bf2f(t.z) * x.z + bf2f(t.w) * x.w;
            }
        }
#pragma unroll
        for (int off = 32; off > 0; off >>= 1)
            acc += __shfl_xor(acc, off, 64);
        if (lane == 0) {
            const float bval = isf32 ? ((const float*)bv)[grow]
                                     : bf2f(((const unsigned short*)bv)[grow]);
            out[grow] = tanhf(FPL_GAMMA * acc + bval);
        }
    }
}

// ---------------- generic fallback (round-3 structure) ----------------
template <bool FINAL>
__global__ __launch_bounds__(256) void fpl_step_raw(const void* __restrict__ Av,
                                                    const void* __restrict__ bv,
                                                    int src, int N,
                                                    float* __restrict__ out) {
    extern __shared__ float xsd[];
    const int rowBlocks = N >> 4;
    const int head = blockIdx.x / rowBlocks;
    const int r0   = (blockIdx.x % rowBlocks) << 4;
    const int tid  = threadIdx.x;
    const float4* xg = (const float4*)(g_x[src] + head * N);
    for (int j = tid; j < (N >> 2); j += 256) ((float4*)xsd)[j] = xg[j];
    __syncthreads();
    const int wave = tid >> 6, lane = tid & 63;
    const int row = r0 + (wave << 2);
    float acc0 = 0.f, acc1 = 0.f, acc2 = 0.f, acc3 = 0.f;
    const bool isf32 = (g_is_f32 != 0);
    if (isf32) {
        const float* A0 = (const float*)Av + (size_t)(head * N + row) * N;
        for (int cb = 0; cb < N; cb += 256) {
            const int c = cb + (lane << 2);
            const float4 xv = *(const float4*)(xsd + c);
            const float4 a0 = *(const float4*)(A0 + c);
            const float4 a1 = *(const float4*)(A0 + N + c);
            const float4 a2 = *(const float4*)(A0 + 2 * N + c);
            const float4 a3 = *(const float4*)(A0 + 3 * N + c);
            acc0 += a0.x*xv.x + a0.y*xv.y + a0.z*xv.z + a0.w*xv.w;
            acc1 += a1.x*xv.x + a1.y*xv.y + a1.z*xv.z + a1.w*xv.w;
            acc2 += a2.x*xv.x + a2.y*xv.y + a2.z*xv.z + a2.w*xv.w;
            acc3 += a3.x*xv.x + a3.y*xv.y + a3.z*xv.z + a3.w*xv.w;
        }
    } else {
        const unsigned short* A0 = (const unsigned short*)Av + (size_t)(head * N + row) * N;
        for (int cb = 0; cb < N; cb += 256) {
            const int c = cb + (lane << 2);
            const float4 xv = *(const float4*)(xsd + c);
            const ushort4 a0 = *(const ushort4*)(A0 + c);
            const ushort4 a1 = *(const ushort4*)(A0 + N + c);
            const ushort4 a2 = *(const ushort4*)(A0 + 2 * N + c);
            const ushort4 a3 = *(const ushort4*)(A0 + 3 * N + c);
            acc0 += bf2f(a0.x)*xv.x + bf2f(a0.y)*xv.y + bf2f(a0.z)*xv.z + bf2f(a0.w)*xv.w;
            acc1 += bf2f(a1.x)*xv.x + bf2f(a1.y)*xv.y + bf2f(a1.z)*xv.z + bf2f(a1.w)*xv.w;
            acc2 += bf2f(a2.x)*xv.x + bf2f(a2.y)*xv.y + bf2f(a2.z)*xv.z + bf2f(a2.w)*xv.w;
            acc3 += bf2f(a3.x)*xv.x + bf2f(a3.y)*xv.y + bf2f(a3.z)*xv.z + bf2f(a3.w)*xv.w;
        }
    }
#pragma unroll
    for (int off = 32; off > 0; off >>= 1) {
        acc0 += __shfl_xor(acc0, off, 64);
        acc1 += __shfl_xor(acc1, off, 64);
        acc2 += __shfl_xor(acc2, off, 64);
        acc3 += __shfl_xor(acc3, off, 64);
    }
    if (lane < 4) {
        float acc = (lane == 0) ? acc0 : (lane == 1) ? acc1 : (lane == 2) ? acc2 : acc3;
        const int idx = head * N + row + lane;
        const float bval = isf32 ? ((const float*)bv)[idx]
                                 : bf2f(((const unsigned short*)bv)[idx]);
        const float y = tanhf(FPL_GAMMA * acc + bval);
        if (FINAL) out[idx] = y;
        else       g_x[1 - src][idx] = y;
    }
}

extern "C" void kernel_launch(void* const* d_in, const int* in_sizes, int n_in,
                              void* d_out, int out_size, void* d_ws, size_t ws_size,
                              hipStream_t stream) {
    (void)d_ws; (void)ws_size; (void)n_in; (void)out_size;
    const void* A = d_in[0];
    const void* b = d_in[1];
    long szA = in_sizes[0], szb = in_sizes[1];
    if (szA < szb) { const void* t = A; A = b; b = t; long s = szA; szA = szb; szb = s; }
    const int HN = (int)szb;
    const int N  = (int)(szA / szb);
    float* out = (float*)d_out;

    // probe bumps the tag epoch (replay-safe namespacing) + dtype detect
    fpl_probe<<<dim3(1), dim3(256), 0, stream>>>((const unsigned short*)A);

    bool done = false;
    if (N == COOP_N && HN == COOP_HN) {
        void* args[] = { (void*)&A, (void*)&b, (void*)&out };
        hipError_t rc = hipLaunchCooperativeKernel((const void*)fpl_coop,
                                                   dim3(256), dim3(512),
                                                   args, 0, stream);
        done = (rc == hipSuccess);
    }
    if (!done) {
        fpl_init<<<dim3((HN + 255) / 256), dim3(256), 0, stream>>>(b, HN);
        const int grid = HN >> 4;
        const size_t lds = (size_t)N * sizeof(float);
        int src = 0;
        for (int s = 0; s < FB_STEPS; ++s) {
            fpl_step_raw<false><<<dim3(grid), dim3(256), lds, stream>>>(A, b, src, N, nullptr);
            src ^= 1;
        }
        fpl_step_raw<true><<<dim3(grid), dim3(256), lds, stream>>>(A, b, src, N, out);
    }
}

// Round 8
// 277.428 us; speedup vs baseline: 1.0766x; 1.0766x over previous
//
#include <hip/hip_runtime.h>
#include <hip/hip_bf16.h>

// FixedPointLayer: x_{k+1} = tanh(GAMMA * A_h @ x_k + b_h). fp32 in/out.
// Round-17: R16's pipelined exchange with a compile-safe bind.
// R16 failed to compile: gfx950 inline asm can't tie register-TUPLE
// in-outs ("+v"(uint4)); scalar 32-bit ties are supported. Theory
// unchanged: R10/R11/R14/R15 showed four sync protocols all cost
// ~7.6us/step because the uncached exchange ops sit SERIALIZED in the
// step's dependency chain with only 2 waves/SIMD to hide ~1us
// system-scope RTTs. Staleness-1 Jacobi (validated bit-identical in
// R14/R15) needs peer data at level >= i for step i+1 -- available a
// full step early. Pipeline:
//   step start: ISSUE tagged reload (2x dwordx4 sc0sc1, no wait)
//   matvec+reduce (~2us) runs while loads fly
//   bind: s_waitcnt vmcnt(0) tying all 8 dwords as scalar "+v" outputs
//         (uses can't be scheduled before) + sched_barrier (rule 18)
//   accept peers at level >= i (own rows excluded; written fresh from
//   registers); store own rows AFTER the bind -> ack never blocks.
// Critical path becomes compute-only (~2.5us/step). Acceptance passes
// first-try in steady state; bounded retries (POLL_CAP); cannot hang.

#define FPL_GAMMA 0.9f
#define INT8_STEPS 13           // async steps (staleness-1 margin, proven)
#define FB_STEPS 15             // fallback keeps original count
#define COOP_H 8
#define COOP_N 2048
#define COOP_HN (COOP_H * COOP_N)
#define MAX_HN 65536
#define SWZ4(i) ((i) ^ (((i) >> 3) & 7))   // float4-index LDS swizzle for xs
#define POLL_CAP (1u << 22)                // safety valve: fail, don't hang

__device__ float g_x[2][MAX_HN];                 // fallback ping-pong iterate
__device__ __align__(16) uint2 g_xt[MAX_HN];     // coop: {bits(x), tag} per row
__device__ int   g_is_f32;                       // 1 if fp32 inputs, 0 if bf16
__device__ unsigned int g_epoch;                 // bumped by probe each launch

__device__ __forceinline__ float bf2f(unsigned short u) {
    union { unsigned int i; float f; } v; v.i = ((unsigned int)u) << 16; return v.f;
}

// ---- proven system-scope transport (R11/R14/R15: correct 4x on HW) ----
__device__ __forceinline__ unsigned int ld_cp32(const void* p) {
    unsigned int r;
    asm volatile("global_load_dword %0, %1, off sc0 sc1\n\ts_waitcnt vmcnt(0)"
                 : "=v"(r) : "v"(p) : "memory");
    return r;
}
__device__ __forceinline__ void st_cp64(void* p, uint2 v) {
    asm volatile("global_store_dwordx2 %0, %1, off sc0 sc1"
                 :: "v"(p), "v"(v) : "memory");
}
// blocking pair-load (retry path / final barrier)
__device__ __forceinline__ void ld2_cp128(const void* p, uint4& a, uint4& b) {
    asm volatile("global_load_dwordx4 %0, %2, off sc0 sc1\n\t"
                 "global_load_dwordx4 %1, %3, off sc0 sc1\n\t"
                 "s_waitcnt vmcnt(0)"
                 : "=&v"(a), "=&v"(b)
                 : "v"(p), "v"((const void*)((const char*)p + 16))
                 : "memory");
}
// pipelined pair-load: issue only (no wait). Output tuples are supported.
__device__ __forceinline__ void ld2_issue(const void* p, uint4& a, uint4& b) {
    asm volatile("global_load_dwordx4 %0, %2, off sc0 sc1\n\t"
                 "global_load_dwordx4 %1, %3, off sc0 sc1"
                 : "=&v"(a), "=&v"(b)
                 : "v"(p), "v"((const void*)((const char*)p + 16))
                 : "memory");
}
// bind: wait, tying each dword as a scalar "+v" (supported) so every use
// of the prefetched values is data-dependent on the wait.
__device__ __forceinline__ void ld2_bind(uint4& a, uint4& b) {
    asm volatile("s_waitcnt vmcnt(0)"
                 : "+v"(a.x), "+v"(a.y), "+v"(a.z), "+v"(a.w),
                   "+v"(b.x), "+v"(b.y), "+v"(b.z), "+v"(b.w)
                 :: "memory");
    __builtin_amdgcn_sched_barrier(0);
}

// Input dtype probe (parallelized) + epoch bump (tag namespace: replay-safe,
// stale tags from prior launches are < this launch's base).
__global__ __launch_bounds__(256) void fpl_probe(const unsigned short* __restrict__ A) {
    const int t = threadIdx.x;
    if (t == 0) g_epoch = g_epoch + 1u;
    if (t < 64) {
        int bad = 0;
#pragma unroll
        for (int k = 0; k < 4; ++k) {
            const float av = fabsf(bf2f(A[(t << 2) + k]));
            if (!(av <= 1e3f)) bad = 1;
        }
        const unsigned long long any = __ballot(bad);
        if (t == 0) g_is_f32 = (any != 0ull) ? 1 : 0;
    }
}

// x1 = tanh(b) into g_x[0] -- FALLBACK path only (coop computes x1 locally).
__global__ __launch_bounds__(256) void fpl_init(const void* __restrict__ bv, int hn) {
    int i = blockIdx.x * 256 + threadIdx.x;
    if (i < hn) {
        float bval = g_is_f32 ? ((const float*)bv)[i]
                              : bf2f(((const unsigned short*)bv)[i]);
        g_x[0][i] = tanhf(bval);
    }
}

// Decode 4 int8 lanes of w against float4 x into acc.
__device__ __forceinline__ float dec4(unsigned int w, const float4 x, float acc) {
    acc = fmaf((float)((int)(w << 24) >> 24), x.x, acc);
    acc = fmaf((float)((int)(w << 16) >> 24), x.y, acc);
    acc = fmaf((float)((int)(w <<  8) >> 24), x.z, acc);
    acc = fmaf((float)((int)w >> 24),         x.w, acc);
    return acc;
}

// Quantize one row (held in v4[8], this wave's 2048 cols) into LDS int8.
__device__ __forceinline__ void quant_row(const float4* v4, int lrow, int lane,
                                          unsigned int* aq, float* rowscale) {
    float m = 0.f;
#pragma unroll
    for (int k = 0; k < 8; ++k)
        m = fmaxf(m, fmaxf(fmaxf(fabsf(v4[k].x), fabsf(v4[k].y)),
                           fmaxf(fabsf(v4[k].z), fabsf(v4[k].w))));
#pragma unroll
    for (int off = 32; off > 0; off >>= 1)
        m = fmaxf(m, __shfl_xor(m, off, 64));
    m = fmaxf(m, 1e-30f);
    const float inv = 127.0f / m;
    if (lane == 0) rowscale[lrow] = m * (1.0f / 127.0f);
    unsigned int* aqr = aq + lrow * 512;
#pragma unroll
    for (int k = 0; k < 8; ++k) {
        const int q0 = (int)rintf(v4[k].x * inv);
        const int q1 = (int)rintf(v4[k].y * inv);
        const int q2 = (int)rintf(v4[k].z * inv);
        const int q3 = (int)rintf(v4[k].w * inv);
        aqr[(k << 6) + lane] = (unsigned int)(q0 & 255)
                             | ((unsigned int)(q1 & 255) << 8)
                             | ((unsigned int)(q2 & 255) << 16)
                             | ((unsigned int)(q3 & 255) << 24);
    }
}

// ---------------- persistent cooperative solver ----------------
// Grid 256 x 512 (1 block/CU by LDS). 32 blocks/head, 64 rows/block.
__global__ __launch_bounds__(512)
void fpl_coop(const void* __restrict__ Av,
              const void* __restrict__ bv,
              float* __restrict__ out) {
    __shared__ unsigned int aq[64 * 512];   // 64 rows x 2048 int8 = 128 KiB
    __shared__ float xs[COOP_N];            // 8 KiB: head's x (SWZ4 layout)
    __shared__ float red[64 * 65];          // 16.6 KiB: partials, padded
    __shared__ float rowscale[64];          // 256 B
    __shared__ unsigned int sh_base;        // epoch<<6 (tag namespace)

    const int tid  = threadIdx.x;
    const int wave = tid >> 6;
    const int lane = tid & 63;
    const int bid  = blockIdx.x;             // 0..255
    const int head = bid & 7;
    const int jblk = bid >> 3;               // block index within head, 0..31
    const int rowBase = jblk << 6;           // 64 rows/block
    const bool isf32 = (g_is_f32 != 0);      // wave-uniform
    const int lrow0 = wave << 3;             // wave's first local row
    // thread t reloads head-relative rows 4t..4t+3; own iff t>>4 == jblk
    const bool ownRange = ((tid >> 4) == jblk);

    if (tid == 0) sh_base = ld_cp32(&g_epoch) << 6;

    // ---- prologue: quantize my wave's 8 rows into LDS int8 ----
    if (isf32) {
        const float* Ab = (const float*)Av;
        const size_t grow0 = (size_t)(head * COOP_N + rowBase + lrow0);
        float4 cur[8], nxt[8];
        {
            const float* Ar = Ab + (grow0 << 11);
#pragma unroll
            for (int k = 0; k < 8; ++k)
                cur[k] = *(const float4*)(Ar + ((k << 8) + (lane << 2)));
        }
#pragma unroll 1
        for (int r = 0; r < 8; ++r) {
            if (r < 7) {
                const float* Ar = Ab + ((grow0 + r + 1) << 11);
#pragma unroll
                for (int k = 0; k < 8; ++k)
                    nxt[k] = *(const float4*)(Ar + ((k << 8) + (lane << 2)));
            }
            quant_row(cur, lrow0 + r, lane, aq, rowscale);
#pragma unroll
            for (int k = 0; k < 8; ++k) cur[k] = nxt[k];
        }
    } else {
#pragma unroll 1
        for (int r = 0; r < 8; ++r) {
            const int lrow = lrow0 + r;
            const size_t grow = (size_t)(head * COOP_N + rowBase + lrow);
            const unsigned short* Ar = (const unsigned short*)Av + (grow << 11);
            float4 v4[8];
#pragma unroll
            for (int k = 0; k < 8; ++k) {
                const ushort4 t = *(const ushort4*)(Ar + ((k << 8) + (lane << 2)));
                v4[k] = make_float4(bf2f(t.x), bf2f(t.y), bf2f(t.z), bf2f(t.w));
            }
            quant_row(v4, lrow, lane, aq, rowscale);
        }
    }

    // ---- local x1 = tanh(b): every block fills the head's FULL x1 in LDS ----
    {
        float4 bb;
        if (isf32) bb = ((const float4*)bv)[(head << 9) + tid];
        else {
            const ushort4 t = ((const ushort4*)bv)[(head << 9) + tid];
            bb = make_float4(bf2f(t.x), bf2f(t.y), bf2f(t.z), bf2f(t.w));
        }
        ((float4*)xs)[SWZ4(tid)] =
            make_float4(tanhf(bb.x), tanhf(bb.y), tanhf(bb.z), tanhf(bb.w));
    }

    // Writer threads (tid%8==0) own local row rl=tid>>3; preload b.
    const int rl   = tid >> 3;               // 0..63
    const int gRow = head * COOP_N + rowBase + rl;
    float breg = 0.f;
    if ((tid & 7) == 0)
        breg = isf32 ? ((const float*)bv)[gRow]
                     : bf2f(((const unsigned short*)bv)[gRow]);

    __syncthreads();                          // aq + rowscale + xs + sh_base
    const unsigned int base = sh_base;        // tag namespace for this launch
    const float sreg = rowscale[rl];          // writer's row scale
    const float4* xsf4 = (const float4*)xs;
    const int c = tid & 7;                    // writer iff c==0

    // publish my level-1 chunk {tanh(b), base+1} (same bits as LDS x1)
    if (c == 0)
        st_cp64(&g_xt[gRow], make_uint2(__float_as_uint(tanhf(breg)), base + 1u));

    const uint4* const gx4 = (const uint4*)&g_xt[head << 11]; // 1024 uint4/head
    const void* const myp  = (const void*)(gx4 + (tid << 1)); // rows 4t..4t+3
    uint4 pa, pb;                              // pipelined reload registers

    // ---- pipelined async int8 iterations ----
    for (int i = 1; i <= INT8_STEPS; ++i) {
        // (1) ISSUE next-input reload (peers' level >= i published a full
        //     step ago); flies under the matvec below.
        if (i < INT8_STEPS) ld2_issue(myp, pa, pb);

        // (2) matvec from xs (LDS only)
        float acc[8];
#pragma unroll
        for (int r = 0; r < 8; ++r) acc[r] = 0.f;
#pragma unroll
        for (int j = 0; j < 2; ++j) {
            const int bb = (j << 8) + (lane << 2);       // f4 idx == u32 idx
            const float4 x0 = xsf4[SWZ4(bb + 0)];
            const float4 x1 = xsf4[SWZ4(bb + 1)];
            const float4 x2 = xsf4[SWZ4(bb + 2)];
            const float4 x3 = xsf4[SWZ4(bb + 3)];
#pragma unroll
            for (int r = 0; r < 8; ++r) {
                const uint4 w = *(const uint4*)(aq + (lrow0 + r) * 512 + bb);
                float a = acc[r];
                a = dec4(w.x, x0, a);
                a = dec4(w.y, x1, a);
                a = dec4(w.z, x2, a);
                a = dec4(w.w, x3, a);
                acc[r] = a;
            }
        }

        // (3) transpose partials via LDS + reduce -> own-row value
#pragma unroll
        for (int r = 0; r < 8; ++r)
            red[(lrow0 + r) * 65 + lane] = acc[r];
        __syncthreads();
        const float* rr = &red[rl * 65 + (c << 3)];
        float v = ((rr[0] + rr[1]) + (rr[2] + rr[3]))
                + ((rr[4] + rr[5]) + (rr[6] + rr[7]));
        v += __shfl_xor(v, 1, 64);
        v += __shfl_xor(v, 2, 64);
        v += __shfl_xor(v, 4, 64);
        const float vnew = tanhf(FPL_GAMMA * sreg * v + breg);  // valid iff c==0

        if (i < INT8_STEPS) {
            // (4) bind prefetch (loads done; prev store drained long ago)
            ld2_bind(pa, pb);
            // (5) accept peers at level >= i (own rows excluded: fresh below)
            const unsigned int need = base + (unsigned int)i;
            int ok = ownRange ? 1
                   : (int)((pa.y >= need) & (pa.w >= need)
                         & (pb.y >= need) & (pb.w >= need));
            for (unsigned int it = 0; !__all(ok) && it < POLL_CAP; ++it) {
                __builtin_amdgcn_s_sleep(1);
                ld2_cp128(myp, pa, pb);
                ok = ownRange ? 1
                   : (int)((pa.y >= need) & (pa.w >= need)
                         & (pb.y >= need) & (pb.w >= need));
            }
            if (!ownRange)
                ((float4*)xs)[SWZ4(tid)] =
                    make_float4(__uint_as_float(pa.x), __uint_as_float(pa.z),
                                __uint_as_float(pb.x), __uint_as_float(pb.z));
            if (c == 0) {   // own rows: freshest value, straight from reg
                const int orow = rowBase + rl;
                xs[SWZ4(orow >> 2) * 4 + (orow & 3)] = vnew;
            }
        }

        // (6) publish own rows AFTER the bind -> store ack never blocks
        if (c == 0)
            st_cp64(&g_xt[gRow],
                    make_uint2(__float_as_uint(vnew),
                               base + (unsigned int)(i + 1)));

        if (i < INT8_STEPS) __syncthreads();   // xs ready for next matvec
    }

    // ---- one true barrier: all rows at final level S+1, then exact step ----
    {
        const unsigned int need = base + (unsigned int)(INT8_STEPS + 1);
        uint4 a, b;
        for (unsigned int it = 0; it < POLL_CAP; ++it) {
            ld2_cp128(myp, a, b);
            const int ok = (a.y >= need) & (a.w >= need)
                         & (b.y >= need) & (b.w >= need);
            if (__all(ok)) break;
            __builtin_amdgcn_s_sleep(1);
        }
        ((float4*)xs)[SWZ4(tid)] =
            make_float4(__uint_as_float(a.x), __uint_as_float(a.z),
                        __uint_as_float(b.x), __uint_as_float(b.z));
        __syncthreads();
    }

    // ---- final differentiable step with EXACT A (streamed, L3-resident) ----
#pragma unroll 1
    for (int r = 0; r < 8; ++r) {
        const int lrow = lrow0 + r;
        const size_t grow = (size_t)(head * COOP_N + rowBase + lrow);
        float acc = 0.f;
        if (isf32) {
            const float* Ar = (const float*)Av + (grow << 11);
#pragma unroll
            for (int k = 0; k < 8; ++k) {
                const float4 a = *(const float4*)(Ar + ((k << 8) + (lane << 2)));
                const float4 x = xsf4[SWZ4((k << 6) + lane)];
                acc += a.x * x.x + a.y * x.y + a.z * x.z + a.w * x.w;
            }
        } else {
            const unsigned short* Ar = (const unsigned short*)Av + (grow << 11);
#pragma unroll
            for (int k = 0; k < 8; ++k) {
                const ushort4 t = *(const ushort4*)(Ar + ((k << 8) + (lane << 2)));
                const float4 x = xsf4[SWZ4((k << 6) + lane)];
                acc += bf2f(t.x) * x.x + bf2f(t.y) * x.y
                     + bf2f(t.z) * x.z + bf2f(t.w) * x.w;
            }
        }
#pragma unroll
        for (int off = 32; off > 0; off >>= 1)
            acc += __shfl_xor(acc, off, 64);
        if (lane == 0) {
            const float bval = isf32 ? ((const float*)bv)[grow]
                                     : bf2f(((const unsigned short*)bv)[grow]);
            out[grow] = tanhf(FPL_GAMMA * acc + bval);
        }
    }
}

// ---------------- generic fallback (round-3 structure) ----------------
template <bool FINAL>
__global__ __launch_bounds__(256) void fpl_step_raw(const void* __restrict__ Av,
                                                    const void* __restrict__ bv,
                                                    int src, int N,
                                                    float* __restrict__ out) {
    extern __shared__ float xsd[];
    const int rowBlocks = N >> 4;
    const int head = blockIdx.x / rowBlocks;
    const int r0   = (blockIdx.x % rowBlocks) << 4;
    const int tid  = threadIdx.x;
    const float4* xg = (const float4*)(g_x[src] + head * N);
    for (int j = tid; j < (N >> 2); j += 256) ((float4*)xsd)[j] = xg[j];
    __syncthreads();
    const int wave = tid >> 6, lane = tid & 63;
    const int row = r0 + (wave << 2);
    float acc0 = 0.f, acc1 = 0.f, acc2 = 0.f, acc3 = 0.f;
    const bool isf32 = (g_is_f32 != 0);
    if (isf32) {
        const float* A0 = (const float*)Av + (size_t)(head * N + row) * N;
        for (int cb = 0; cb < N; cb += 256) {
            const int c = cb + (lane << 2);
            const float4 xv = *(const float4*)(xsd + c);
            const float4 a0 = *(const float4*)(A0 + c);
            const float4 a1 = *(const float4*)(A0 + N + c);
            const float4 a2 = *(const float4*)(A0 + 2 * N + c);
            const float4 a3 = *(const float4*)(A0 + 3 * N + c);
            acc0 += a0.x*xv.x + a0.y*xv.y + a0.z*xv.z + a0.w*xv.w;
            acc1 += a1.x*xv.x + a1.y*xv.y + a1.z*xv.z + a1.w*xv.w;
            acc2 += a2.x*xv.x + a2.y*xv.y + a2.z*xv.z + a2.w*xv.w;
            acc3 += a3.x*xv.x + a3.y*xv.y + a3.z*xv.z + a3.w*xv.w;
        }
    } else {
        const unsigned short* A0 = (const unsigned short*)Av + (size_t)(head * N + row) * N;
        for (int cb = 0; cb < N; cb += 256) {
            const int c = cb + (lane << 2);
            const float4 xv = *(const float4*)(xsd + c);
            const ushort4 a0 = *(const ushort4*)(A0 + c);
            const ushort4 a1 = *(const ushort4*)(A0 + N + c);
            const ushort4 a2 = *(const ushort4*)(A0 + 2 * N + c);
            const ushort4 a3 = *(const ushort4*)(A0 + 3 * N + c);
            acc0 += bf2f(a0.x)*xv.x + bf2f(a0.y)*xv.y + bf2f(a0.z)*xv.z + bf2f(a0.w)*xv.w;
            acc1 += bf2f(a1.x)*xv.x + bf2f(a1.y)*xv.y + bf2f(a1.z)*xv.z + bf2f(a1.w)*xv.w;
            acc2 += bf2f(a2.x)*xv.x + bf2f(a2.y)*xv.y + bf2f(a2.z)*xv.z + bf2f(a2.w)*xv.w;
            acc3 += bf2f(a3.x)*xv.x + bf2f(a3.y)*xv.y + bf2f(a3.z)*xv.z + bf2f(a3.w)*xv.w;
        }
    }
#pragma unroll
    for (int off = 32; off > 0; off >>= 1) {
        acc0 += __shfl_xor(acc0, off, 64);
        acc1 += __shfl_xor(acc1, off, 64);
        acc2 += __shfl_xor(acc2, off, 64);
        acc3 += __shfl_xor(acc3, off, 64);
    }
    if (lane < 4) {
        float acc = (lane == 0) ? acc0 : (lane == 1) ? acc1 : (lane == 2) ? acc2 : acc3;
        const int idx = head * N + row + lane;
        const float bval = isf32 ? ((const float*)bv)[idx]
                                 : bf2f(((const unsigned short*)bv)[idx]);
        const float y = tanhf(FPL_GAMMA * acc + bval);
        if (FINAL) out[idx] = y;
        else       g_x[1 - src][idx] = y;
    }
}

extern "C" void kernel_launch(void* const* d_in, const int* in_sizes, int n_in,
                              void* d_out, int out_size, void* d_ws, size_t ws_size,
                              hipStream_t stream) {
    (void)d_ws; (void)ws_size; (void)n_in; (void)out_size;
    const void* A = d_in[0];
    const void* b = d_in[1];
    long szA = in_sizes[0], szb = in_sizes[1];
    if (szA < szb) { const void* t = A; A = b; b = t; long s = szA; szA = szb; szb = s; }
    const int HN = (int)szb;
    const int N  = (int)(szA / szb);
    float* out = (float*)d_out;

    // probe bumps the tag epoch (replay-safe namespacing) + dtype detect
    fpl_probe<<<dim3(1), dim3(256), 0, stream>>>((const unsigned short*)A);

    bool done = false;
    if (N == COOP_N && HN == COOP_HN) {
        void* args[] = { (void*)&A, (void*)&b, (void*)&out };
        hipError_t rc = hipLaunchCooperativeKernel((const void*)fpl_coop,
                                                   dim3(256), dim3(512),
                                                   args, 0, stream);
        done = (rc == hipSuccess);
    }
    if (!done) {
        fpl_init<<<dim3((HN + 255) / 256), dim3(256), 0, stream>>>(b, HN);
        const int grid = HN >> 4;
        const size_t lds = (size_t)N * sizeof(float);
        int src = 0;
        for (int s = 0; s < FB_STEPS; ++s) {
            fpl_step_raw<false><<<dim3(grid), dim3(256), lds, stream>>>(A, b, src, N, nullptr);
            src ^= 1;
        }
        fpl_step_raw<true><<<dim3(grid), dim3(256), lds, stream>>>(A, b, src, N, out);
    }
}